// Round 5
// baseline (253.410 us; speedup 1.0000x reference)
//
#include <hip/hip_runtime.h>
#include <cmath>

#define BS   2
#define SEQ  2048
#define DM   1024
#define NH   16
#define HD   64
#define D3   3072
#define MROWS 4096
#define KVBLK 64
#define QBLK  64
#define NTILES (SEQ / KVBLK)   // 32

typedef _Float16 f16;
typedef __attribute__((ext_vector_type(4))) _Float16 half4;
typedef __attribute__((ext_vector_type(8))) _Float16 half8;
typedef __attribute__((ext_vector_type(4))) float f32x4;
typedef unsigned int u32;
typedef __attribute__((ext_vector_type(4))) u32 u32x4;

__device__ __forceinline__ void async_cp16(const void* g, void* s) {
    __builtin_amdgcn_global_load_lds(
        (const __attribute__((address_space(1))) u32*)g,
        (__attribute__((address_space(3))) u32*)s, 16, 0, 0);
}

// ---------------------------------------------------------------------------
// Conversion passes
// ---------------------------------------------------------------------------
__global__ __launch_bounds__(256) void conv_concat_kernel(
    const float* __restrict__ q, const float* __restrict__ k,
    const float* __restrict__ v, f16* __restrict__ out)
{
    const int seg = blockIdx.x;            // 0..2
    const int row = blockIdx.y;            // 0..4095
    const int c   = threadIdx.x * 4;
    const float* src = (seg == 0 ? q : (seg == 1 ? k : v)) + (size_t)row * DM + c;
    float4 x = *(const float4*)src;
    half4 h = {(f16)x.x, (f16)x.y, (f16)x.z, (f16)x.w};
    *(half4*)&out[(size_t)row * D3 + seg * DM + c] = h;
}

__global__ __launch_bounds__(256) void conv_plain_kernel(
    const float* __restrict__ src, f16* __restrict__ dst, int n4)
{
    int i = blockIdx.x * 256 + threadIdx.x;
    const int stride = gridDim.x * 256;
    for (; i < n4; i += stride) {
        float4 x = *(const float4*)&src[(size_t)i * 4];
        half4 h = {(f16)x.x, (f16)x.y, (f16)x.z, (f16)x.w};
        *(half4*)&dst[(size_t)i * 4] = h;
    }
}

// ---------------------------------------------------------------------------
// fp16 MFMA GEMM (m97 structure) — unchanged
// ---------------------------------------------------------------------------
template<int KDIM, int NDIM, bool F16OUT>
__global__ __launch_bounds__(256) void gemm_f16_kernel(
    const f16* __restrict__ A, const f16* __restrict__ W,
    const float* __restrict__ bias, void* __restrict__ Cout)
{
    __shared__ f16 As[128 * 32];
    __shared__ f16 Ws[128 * 32];

    const int tid  = threadIdx.x;
    const int lane = tid & 63;
    const int wave = tid >> 6;
    const int l15  = lane & 15;
    const int lg   = lane >> 4;
    const int wm   = wave >> 1;
    const int wn   = wave & 1;

    const int cpx = gridDim.x >> 3;
    const int lid = (blockIdx.x & 7) * cpx + (blockIdx.x >> 3);
    const int NT  = NDIM / 128;
    const int tM0 = (lid / NT) * 128;
    const int tN0 = (lid % NT) * 128;

    const int srow = lane >> 2;
    const int sch  = lane & 3;
    const int ssc  = sch ^ ((srow >> 1) & 3);

    const f16* gA0 = A + (size_t)(tM0 + wave * 32      + srow) * KDIM + ssc * 8;
    const f16* gA1 = A + (size_t)(tM0 + wave * 32 + 16 + srow) * KDIM + ssc * 8;
    const f16* gW0 = W + (size_t)(tN0 + wave * 32      + srow) * KDIM + ssc * 8;
    const f16* gW1 = W + (size_t)(tN0 + wave * 32 + 16 + srow) * KDIM + ssc * 8;
    f16* lA0 = &As[(wave * 32)      * 32];
    f16* lA1 = &As[(wave * 32 + 16) * 32];
    f16* lW0 = &Ws[(wave * 32)      * 32];
    f16* lW1 = &Ws[(wave * 32 + 16) * 32];

    f32x4 acc[4][4];
#pragma unroll
    for (int i = 0; i < 4; ++i)
#pragma unroll
        for (int j = 0; j < 4; ++j) acc[i][j] = (f32x4){0.f, 0.f, 0.f, 0.f};

    const int fsw = (lg ^ ((l15 >> 1) & 3)) * 8;
    int aoff[4], woff[4];
#pragma unroll
    for (int mi = 0; mi < 4; ++mi) aoff[mi] = (wm * 64 + mi * 16 + l15) * 32 + fsw;
#pragma unroll
    for (int ni = 0; ni < 4; ++ni) woff[ni] = (wn * 64 + ni * 16 + l15) * 32 + fsw;

    for (int k0 = 0; k0 < KDIM; k0 += 32) {
        __syncthreads();
        async_cp16(gA0 + k0, lA0);
        async_cp16(gA1 + k0, lA1);
        async_cp16(gW0 + k0, lW0);
        async_cp16(gW1 + k0, lW1);
        __syncthreads();

        half8 af[4], wf[4];
#pragma unroll
        for (int mi = 0; mi < 4; ++mi) af[mi] = *(half8*)&As[aoff[mi]];
#pragma unroll
        for (int ni = 0; ni < 4; ++ni) wf[ni] = *(half8*)&Ws[woff[ni]];
#pragma unroll
        for (int mi = 0; mi < 4; ++mi)
#pragma unroll
            for (int ni = 0; ni < 4; ++ni)
                acc[mi][ni] = __builtin_amdgcn_mfma_f32_16x16x32_f16(
                    af[mi], wf[ni], acc[mi][ni], 0, 0, 0);
    }

    float bv[4];
#pragma unroll
    for (int ni = 0; ni < 4; ++ni) bv[ni] = bias[tN0 + wn * 64 + ni * 16 + l15];

#pragma unroll
    for (int mi = 0; mi < 4; ++mi)
#pragma unroll
        for (int ni = 0; ni < 4; ++ni)
#pragma unroll
            for (int r = 0; r < 4; ++r) {
                const int m   = tM0 + wm * 64 + mi * 16 + lg * 4 + r;
                const int col = tN0 + wn * 64 + ni * 16 + l15;
                const float val = acc[mi][ni][r] + bv[ni];
                if constexpr (F16OUT)
                    ((f16*)Cout)[(size_t)m * NDIM + col] = (f16)val;
                else
                    ((float*)Cout)[(size_t)m * NDIM + col] = val;
            }
}

// ---------------------------------------------------------------------------
// fp16 MFMA flash attention, QBLK=64 (1 row-tile/wave), grid 1024 = 4/CU.
// LDS 40KB: K dbuf 16K + Vt dbuf 16K + Pl 8K. XCD-chunked block swizzle.
// ---------------------------------------------------------------------------

#define V_STORE(VtN, va, vb) do {                                             \
    u32x4 aw_ = __builtin_bit_cast(u32x4, va);                                \
    u32x4 bw_ = __builtin_bit_cast(u32x4, vb);                                \
    _Pragma("unroll")                                                         \
    for (int wd_ = 0; wd_ < 4; ++wd_) {                                       \
        u32 lo_ = __builtin_amdgcn_perm(bw_[wd_], aw_[wd_], 0x05040100u);     \
        u32 hi_ = __builtin_amdgcn_perm(bw_[wd_], aw_[wd_], 0x07060302u);     \
        const int dl_ = vd0 + 2 * wd_;                                        \
        const int dh_ = dl_ + 1;                                              \
        *(u32*)&VtN[dl_ * KVBLK + (((vp >> 2) ^ (dl_ & 7) ^ (dl_ >> 3)) * 8)  \
                    + 2 * (vp & 3)] = lo_;                                    \
        *(u32*)&VtN[dh_ * KVBLK + (((vp >> 2) ^ (dh_ & 7) ^ (dh_ >> 3)) * 8)  \
                    + 2 * (vp & 3)] = hi_;                                    \
    }                                                                         \
} while (0)

#define ATTN_STEP(KhC, VtC, KhN, VtN, TT, PF) do {                            \
    half8 va_ = {}, vb_ = {};                                                 \
    if (PF) {                                                                 \
        const size_t nro_ = (size_t)((TT) + 1) * KVBLK;                       \
        async_cp16(kxsrc + (nro_ + wave * 16 +     krow_l) * D3,              \
                   &KhN[(wave * 16) * HD]);                                   \
        async_cp16(kxsrc + (nro_ + wave * 16 + 8 + krow_l) * D3,              \
                   &KhN[(wave * 16 + 8) * HD]);                               \
        va_ = *(const half8*)(vsrc0 + nro_ * D3);                             \
        vb_ = *(const half8*)(vsrc0 + nro_ * D3 + D3);                        \
    }                                                                         \
    f32x4 sc[4];                                                              \
    _Pragma("unroll")                                                         \
    for (int ct = 0; ct < 4; ++ct) sc[ct] = (f32x4){0.f, 0.f, 0.f, 0.f};      \
    __builtin_amdgcn_s_setprio(1);                                            \
    _Pragma("unroll")                                                         \
    for (int ct = 0; ct < 4; ++ct) {                                          \
        const int krow = ct * 16 + l15;                                       \
        _Pragma("unroll")                                                     \
        for (int ks = 0; ks < 2; ++ks) {                                      \
            half8 kf = *(half8*)&KhC[krow * HD +                              \
                                     (((ks * 4 + lg) ^ (krow & 7)) * 8)];     \
            sc[ct] = __builtin_amdgcn_mfma_f32_16x16x32_f16(                  \
                qf[ks], kf, sc[ct], 0, 0, 0);                                 \
        }                                                                     \
    }                                                                         \
    __builtin_amdgcn_s_setprio(0);                                            \
    _Pragma("unroll")                                                         \
    for (int ct = 0; ct < 4; ++ct)                                            \
        _Pragma("unroll")                                                     \
        for (int r = 0; r < 4; ++r) sc[ct][r] *= 0.125f;                      \
    {                                                                         \
        float mt[4];                                                          \
        _Pragma("unroll")                                                     \
        for (int r = 0; r < 4; ++r)                                           \
            mt[r] = fmaxf(fmaxf(sc[0][r], sc[1][r]),                          \
                          fmaxf(sc[2][r], sc[3][r]));                         \
        _Pragma("unroll")                                                     \
        for (int m = 1; m < 16; m <<= 1)                                      \
            _Pragma("unroll")                                                 \
            for (int r = 0; r < 4; ++r)                                       \
                mt[r] = fmaxf(mt[r], __shfl_xor(mt[r], m));                   \
        float alpha[4], mn[4];                                                \
        _Pragma("unroll")                                                     \
        for (int r = 0; r < 4; ++r) {                                         \
            mn[r] = fmaxf(mrun[r], mt[r]);                                    \
            alpha[r] = __expf(mrun[r] - mn[r]);                               \
            mrun[r] = mn[r];                                                  \
        }                                                                     \
        float ls[4] = {0.f, 0.f, 0.f, 0.f};                                   \
        _Pragma("unroll")                                                     \
        for (int ct = 0; ct < 4; ++ct) {                                      \
            f32x4 v = sc[ct];                                                 \
            _Pragma("unroll")                                                 \
            for (int r = 0; r < 4; ++r) {                                     \
                v[r] = __expf(v[r] - mn[r]);                                  \
                ls[r] += v[r];                                                \
                const int qq = lg * 4 + r;                                    \
                const int chP = (ct * 2 + (l15 >> 3)) ^ (lg << 1);            \
                Pl[pbase + qq * KVBLK + chP * 8 + (l15 & 7)] = (f16)v[r];     \
            }                                                                 \
        }                                                                     \
        _Pragma("unroll")                                                     \
        for (int m = 1; m < 16; m <<= 1)                                      \
            _Pragma("unroll")                                                 \
            for (int r = 0; r < 4; ++r) ls[r] += __shfl_xor(ls[r], m);        \
        _Pragma("unroll")                                                     \
        for (int r = 0; r < 4; ++r) lrun[r] = lrun[r] * alpha[r] + ls[r];     \
        _Pragma("unroll")                                                     \
        for (int dct = 0; dct < 4; ++dct)                                     \
            _Pragma("unroll")                                                 \
            for (int r = 0; r < 4; ++r) oacc[dct][r] *= alpha[r];             \
    }                                                                         \
    __builtin_amdgcn_s_setprio(1);                                            \
    _Pragma("unroll")                                                         \
    for (int ks2 = 0; ks2 < 2; ++ks2) {                                       \
        const int qq = l15;                                                   \
        const int chR = (ks2 * 4 + lg) ^ ((l15 >> 2) << 1);                   \
        half8 pa = *(half8*)&Pl[pbase + qq * KVBLK + chR * 8];                \
        _Pragma("unroll")                                                     \
        for (int dct = 0; dct < 4; ++dct) {                                   \
            const int d = dct * 16 + l15;                                     \
            half8 vf = *(half8*)&VtC[d * KVBLK +                              \
                        (((ks2 * 4 + lg) ^ (d & 7) ^ (d >> 3)) * 8)];         \
            oacc[dct] = __builtin_amdgcn_mfma_f32_16x16x32_f16(               \
                pa, vf, oacc[dct], 0, 0, 0);                                  \
        }                                                                     \
    }                                                                         \
    __builtin_amdgcn_s_setprio(0);                                            \
    if (PF) { V_STORE(VtN, va_, vb_); }                                       \
    __syncthreads();                                                          \
} while (0)

__global__ __launch_bounds__(256, 4) void attn_mfma_kernel(
    const f16* __restrict__ qkvh, f16* __restrict__ attnh)
{
    __shared__ f16 Kh0[KVBLK * HD];       // 8 KB
    __shared__ f16 Kh1[KVBLK * HD];       // 8 KB
    __shared__ f16 Vt0[HD * KVBLK];       // 8 KB  [d][k]
    __shared__ f16 Vt1[HD * KVBLK];       // 8 KB
    __shared__ f16 Pl[4 * 16 * KVBLK];    // 8 KB per-wave [q][k]

    const int tid  = threadIdx.x;
    const int lane = tid & 63;
    const int wave = tid >> 6;
    const int l15  = lane & 15;
    const int lg   = lane >> 4;

    const int nq  = SEQ / QBLK;           // 32
    // XCD-chunked swizzle: 128 consecutive work-ids (4 heads) per XCD
    const int cpx = gridDim.x >> 3;
    const int lid = (blockIdx.x & 7) * cpx + (blockIdx.x >> 3);
    const int b   = lid / (NH * nq);
    const int h   = (lid / nq) % NH;
    const int qc  = lid % nq;
    const int q0  = qc * QBLK + wave * 16;
    const size_t bS = (size_t)b * SEQ;

    // K staging geometry
    const int krow_l = lane >> 3;         // 0..7
    const int kschk  = (lane & 7) ^ krow_l;
    const f16* kxsrc = qkvh + bS * D3 + DM + h * HD + kschk * 8;

    // V staging geometry: thread = 2 k-rows x 8 d
    const int vp  = tid >> 3;             // 0..31
    const int vd0 = (tid & 7) * 8;
    const f16* vsrc0 = qkvh + (bS + 2 * vp) * D3 + 2 * DM + h * HD + vd0;

    // Q fragments (16 rows per wave)
    half8 qf[2];
#pragma unroll
    for (int ks = 0; ks < 2; ++ks)
        qf[ks] = *(const half8*)&qkvh[(bS + q0 + l15) * D3 +
                                      h * HD + ks * 32 + lg * 8];

    f32x4 oacc[4];
#pragma unroll
    for (int dct = 0; dct < 4; ++dct) oacc[dct] = (f32x4){0.f, 0.f, 0.f, 0.f};

    float mrun[4], lrun[4];
#pragma unroll
    for (int r = 0; r < 4; ++r) { mrun[r] = -INFINITY; lrun[r] = 0.f; }

    const int pbase = wave * 16 * KVBLK;

    // prologue: stage tile 0 into buf0
    {
        async_cp16(kxsrc + (size_t)(wave * 16 +     krow_l) * D3, &Kh0[(wave * 16) * HD]);
        async_cp16(kxsrc + (size_t)(wave * 16 + 8 + krow_l) * D3, &Kh0[(wave * 16 + 8) * HD]);
        half8 va_ = *(const half8*)(vsrc0);
        half8 vb_ = *(const half8*)(vsrc0 + D3);
        V_STORE(Vt0, va_, vb_);
        __syncthreads();   // drains gload vmcnt + publishes Vt0
    }

    for (int t = 0; t < NTILES; t += 2) {
        ATTN_STEP(Kh0, Vt0, Kh1, Vt1, t, true);
        ATTN_STEP(Kh1, Vt1, Kh0, Vt0, t + 1, (t + 1) < (NTILES - 1));
    }

    // epilogue
    {
        float inv[4];
#pragma unroll
        for (int r = 0; r < 4; ++r) inv[r] = 1.f / lrun[r];
#pragma unroll
        for (int dct = 0; dct < 4; ++dct)
#pragma unroll
            for (int r = 0; r < 4; ++r) {
                const int qq = q0 + lg * 4 + r;
                attnh[(bS + qq) * DM + h * HD + dct * 16 + l15] =
                    (f16)(oacc[dct][r] * inv[r]);
            }
    }
}

// ---------------------------------------------------------------------------
extern "C" void kernel_launch(void* const* d_in, const int* in_sizes, int n_in,
                              void* d_out, int out_size, void* d_ws, size_t ws_size,
                              hipStream_t stream) {
    const float* q    = (const float*)d_in[0];
    const float* k    = (const float*)d_in[1];
    const float* v    = (const float*)d_in[2];
    const float* Wqkv = (const float*)d_in[3];
    const float* bqkv = (const float*)d_in[4];
    const float* Wo   = (const float*)d_in[5];
    const float* bo   = (const float*)d_in[6];
    float* out = (float*)d_out;

    char* ws = (char*)d_ws;
    f16* Ain    = (f16*)ws;                        // [4096][3072]
    f16* attn_h = (f16*)ws;                        // [4096][1024] (reuse)
    f16* Wo_h   = (f16*)(ws + 16777216);           // [1024][1024] (reuse)
    f16* Wqkv_h = (f16*)(ws + 25165824);           // [3072][3072]
    f16* qkv_h  = (f16*)(ws + 44040192);           // [4096][3072]

    conv_concat_kernel<<<dim3(3, MROWS), 256, 0, stream>>>(q, k, v, Ain);
    conv_plain_kernel<<<2048, 256, 0, stream>>>(Wqkv, Wqkv_h, D3 * D3 / 4);

    gemm_f16_kernel<D3, D3, true><<<dim3((MROWS / 128) * (D3 / 128)), 256, 0, stream>>>(
        Ain, Wqkv_h, bqkv, qkv_h);

    attn_mfma_kernel<<<dim3(BS * NH * (SEQ / QBLK)), 256, 0, stream>>>(qkv_h, attn_h);

    conv_plain_kernel<<<512, 256, 0, stream>>>(Wo, Wo_h, DM * DM / 4);

    gemm_f16_kernel<DM, DM, false><<<dim3((MROWS / 128) * (DM / 128)), 256, 0, stream>>>(
        attn_h, Wo_h, bo, out);
}

// Round 6
// 215.718 us; speedup vs baseline: 1.1747x; 1.1747x over previous
//
#include <hip/hip_runtime.h>
#include <cmath>

#define BS   2
#define SEQ  2048
#define DM   1024
#define NH   16
#define HD   64
#define D3   3072
#define MROWS 4096
#define KVBLK 64
#define QBLK  128
#define NTILES (SEQ / KVBLK)   // 32

// log2(e)/8: folds softmax scale and exp->exp2 conversion into one FMA
#define CSC 0.18033688011112042f

typedef _Float16 f16;
typedef __attribute__((ext_vector_type(4))) _Float16 half4;
typedef __attribute__((ext_vector_type(8))) _Float16 half8;
typedef __attribute__((ext_vector_type(4))) float f32x4;
typedef unsigned int u32;
typedef __attribute__((ext_vector_type(2))) u32 u32x2;
typedef __attribute__((ext_vector_type(4))) u32 u32x4;

__device__ __forceinline__ void async_cp16(const void* g, void* s) {
    __builtin_amdgcn_global_load_lds(
        (const __attribute__((address_space(1))) u32*)g,
        (__attribute__((address_space(3))) u32*)s, 16, 0, 0);
}

// ---------------------------------------------------------------------------
// Conversion passes
// ---------------------------------------------------------------------------
__global__ __launch_bounds__(256) void conv_concat_kernel(
    const float* __restrict__ q, const float* __restrict__ k,
    const float* __restrict__ v, f16* __restrict__ out)
{
    const int seg = blockIdx.x;            // 0..2
    const int row = blockIdx.y;            // 0..4095
    const int c   = threadIdx.x * 4;
    const float* src = (seg == 0 ? q : (seg == 1 ? k : v)) + (size_t)row * DM + c;
    float4 x = *(const float4*)src;
    half4 h = {(f16)x.x, (f16)x.y, (f16)x.z, (f16)x.w};
    *(half4*)&out[(size_t)row * D3 + seg * DM + c] = h;
}

__global__ __launch_bounds__(256) void conv_plain_kernel(
    const float* __restrict__ src, f16* __restrict__ dst, int n4)
{
    int i = blockIdx.x * 256 + threadIdx.x;
    const int stride = gridDim.x * 256;
    for (; i < n4; i += stride) {
        float4 x = *(const float4*)&src[(size_t)i * 4];
        half4 h = {(f16)x.x, (f16)x.y, (f16)x.z, (f16)x.w};
        *(half4*)&dst[(size_t)i * 4] = h;
    }
}

// ---------------------------------------------------------------------------
// fp16 MFMA GEMM (m97 structure) — unchanged
// ---------------------------------------------------------------------------
template<int KDIM, int NDIM, bool F16OUT>
__global__ __launch_bounds__(256) void gemm_f16_kernel(
    const f16* __restrict__ A, const f16* __restrict__ W,
    const float* __restrict__ bias, void* __restrict__ Cout)
{
    __shared__ f16 As[128 * 32];
    __shared__ f16 Ws[128 * 32];

    const int tid  = threadIdx.x;
    const int lane = tid & 63;
    const int wave = tid >> 6;
    const int l15  = lane & 15;
    const int lg   = lane >> 4;
    const int wm   = wave >> 1;
    const int wn   = wave & 1;

    const int cpx = gridDim.x >> 3;
    const int lid = (blockIdx.x & 7) * cpx + (blockIdx.x >> 3);
    const int NT  = NDIM / 128;
    const int tM0 = (lid / NT) * 128;
    const int tN0 = (lid % NT) * 128;

    const int srow = lane >> 2;
    const int sch  = lane & 3;
    const int ssc  = sch ^ ((srow >> 1) & 3);

    const f16* gA0 = A + (size_t)(tM0 + wave * 32      + srow) * KDIM + ssc * 8;
    const f16* gA1 = A + (size_t)(tM0 + wave * 32 + 16 + srow) * KDIM + ssc * 8;
    const f16* gW0 = W + (size_t)(tN0 + wave * 32      + srow) * KDIM + ssc * 8;
    const f16* gW1 = W + (size_t)(tN0 + wave * 32 + 16 + srow) * KDIM + ssc * 8;
    f16* lA0 = &As[(wave * 32)      * 32];
    f16* lA1 = &As[(wave * 32 + 16) * 32];
    f16* lW0 = &Ws[(wave * 32)      * 32];
    f16* lW1 = &Ws[(wave * 32 + 16) * 32];

    f32x4 acc[4][4];
#pragma unroll
    for (int i = 0; i < 4; ++i)
#pragma unroll
        for (int j = 0; j < 4; ++j) acc[i][j] = (f32x4){0.f, 0.f, 0.f, 0.f};

    const int fsw = (lg ^ ((l15 >> 1) & 3)) * 8;
    int aoff[4], woff[4];
#pragma unroll
    for (int mi = 0; mi < 4; ++mi) aoff[mi] = (wm * 64 + mi * 16 + l15) * 32 + fsw;
#pragma unroll
    for (int ni = 0; ni < 4; ++ni) woff[ni] = (wn * 64 + ni * 16 + l15) * 32 + fsw;

    for (int k0 = 0; k0 < KDIM; k0 += 32) {
        __syncthreads();
        async_cp16(gA0 + k0, lA0);
        async_cp16(gA1 + k0, lA1);
        async_cp16(gW0 + k0, lW0);
        async_cp16(gW1 + k0, lW1);
        __syncthreads();

        half8 af[4], wf[4];
#pragma unroll
        for (int mi = 0; mi < 4; ++mi) af[mi] = *(half8*)&As[aoff[mi]];
#pragma unroll
        for (int ni = 0; ni < 4; ++ni) wf[ni] = *(half8*)&Ws[woff[ni]];
#pragma unroll
        for (int mi = 0; mi < 4; ++mi)
#pragma unroll
            for (int ni = 0; ni < 4; ++ni)
                acc[mi][ni] = __builtin_amdgcn_mfma_f32_16x16x32_f16(
                    af[mi], wf[ni], acc[mi][ni], 0, 0, 0);
    }

    float bv[4];
#pragma unroll
    for (int ni = 0; ni < 4; ++ni) bv[ni] = bias[tN0 + wn * 64 + ni * 16 + l15];

#pragma unroll
    for (int mi = 0; mi < 4; ++mi)
#pragma unroll
        for (int ni = 0; ni < 4; ++ni)
#pragma unroll
            for (int r = 0; r < 4; ++r) {
                const int m   = tM0 + wm * 64 + mi * 16 + lg * 4 + r;
                const int col = tN0 + wn * 64 + ni * 16 + l15;
                const float val = acc[mi][ni][r] + bv[ni];
                if constexpr (F16OUT)
                    ((f16*)Cout)[(size_t)m * NDIM + col] = (f16)val;
                else
                    ((float*)Cout)[(size_t)m * NDIM + col] = val;
            }
}

// ---------------------------------------------------------------------------
// fp16 MFMA flash attention, swapped-operand form:
//   SC^T = mfma(K_frag, Q_frag)  -> lane owns one q-row (q = l15), k in-reg
//   softmax: in-lane over 16 + 2 shfl_xor; scalar m/l/alpha per rt
//   P packed via cvt_pkrtz, 8x ds_write_b64 / 8x ds_read_b64 (XOR-l15 swz)
//   O^T = mfma(Vt_frag, P_frag)  -> epilogue half4 stores
// K staged via global_load_lds, V via v_perm transpose; dbuf, 1 barrier/tile.
// ---------------------------------------------------------------------------

#define V_STORE(VtN, va, vb) do {                                             \
    u32x4 aw_ = __builtin_bit_cast(u32x4, va);                                \
    u32x4 bw_ = __builtin_bit_cast(u32x4, vb);                                \
    _Pragma("unroll")                                                         \
    for (int wd_ = 0; wd_ < 4; ++wd_) {                                       \
        u32 lo_ = __builtin_amdgcn_perm(bw_[wd_], aw_[wd_], 0x05040100u);     \
        u32 hi_ = __builtin_amdgcn_perm(bw_[wd_], aw_[wd_], 0x07060302u);     \
        const int dl_ = vd0 + 2 * wd_;                                        \
        const int dh_ = dl_ + 1;                                              \
        *(u32*)&VtN[dl_ * KVBLK + (((vp >> 2) ^ (dl_ & 7) ^ (dl_ >> 3)) * 8)  \
                    + 2 * (vp & 3)] = lo_;                                    \
        *(u32*)&VtN[dh_ * KVBLK + (((vp >> 2) ^ (dh_ & 7) ^ (dh_ >> 3)) * 8)  \
                    + 2 * (vp & 3)] = hi_;                                    \
    }                                                                         \
} while (0)

#define ATTN_STEP(KhC, VtC, KhN, VtN, TT, PF) do {                            \
    half8 va_ = {}, vb_ = {};                                                 \
    if (PF) {                                                                 \
        const size_t nro_ = (size_t)((TT) + 1) * KVBLK;                       \
        async_cp16(kxsrc + (nro_ + wave * 16 +     krow_l) * D3,              \
                   &KhN[(wave * 16) * HD]);                                   \
        async_cp16(kxsrc + (nro_ + wave * 16 + 8 + krow_l) * D3,              \
                   &KhN[(wave * 16 + 8) * HD]);                               \
        va_ = *(const half8*)(vsrc0 + nro_ * D3);                             \
        vb_ = *(const half8*)(vsrc0 + nro_ * D3 + D3);                        \
    }                                                                         \
    f32x4 sc[2][4];                                                           \
    _Pragma("unroll")                                                         \
    for (int rt = 0; rt < 2; ++rt)                                            \
        _Pragma("unroll")                                                     \
        for (int ct = 0; ct < 4; ++ct) sc[rt][ct] = (f32x4){0.f,0.f,0.f,0.f}; \
    __builtin_amdgcn_s_setprio(1);                                            \
    _Pragma("unroll")                                                         \
    for (int ct = 0; ct < 4; ++ct) {                                          \
        const int krow = ct * 16 + l15;                                       \
        _Pragma("unroll")                                                     \
        for (int ks = 0; ks < 2; ++ks) {                                      \
            half8 kf = *(half8*)&KhC[krow * HD +                              \
                                     (((ks * 4 + lg) ^ (krow & 7)) * 8)];     \
            _Pragma("unroll")                                                 \
            for (int rt = 0; rt < 2; ++rt)                                    \
                sc[rt][ct] = __builtin_amdgcn_mfma_f32_16x16x32_f16(          \
                    kf, qf[rt][ks], sc[rt][ct], 0, 0, 0);                     \
        }                                                                     \
    }                                                                         \
    __builtin_amdgcn_s_setprio(0);                                            \
    _Pragma("unroll")                                                         \
    for (int rt = 0; rt < 2; ++rt) {                                          \
        float mt = sc[rt][0][0];                                              \
        _Pragma("unroll")                                                     \
        for (int ct = 0; ct < 4; ++ct)                                        \
            _Pragma("unroll")                                                 \
            for (int r = 0; r < 4; ++r)                                       \
                if (ct || r) mt = fmaxf(mt, sc[rt][ct][r]);                   \
        mt = fmaxf(mt, __shfl_xor(mt, 16));                                   \
        mt = fmaxf(mt, __shfl_xor(mt, 32));                                   \
        const float mn = fmaxf(mrun[rt], mt * CSC);                           \
        const float alpha = exp2f(mrun[rt] - mn);                             \
        mrun[rt] = mn;                                                        \
        float pv_[4][4];                                                      \
        float ls = 0.f;                                                       \
        _Pragma("unroll")                                                     \
        for (int ct = 0; ct < 4; ++ct)                                        \
            _Pragma("unroll")                                                 \
            for (int r = 0; r < 4; ++r) {                                     \
                pv_[ct][r] = exp2f(fmaf(sc[rt][ct][r], CSC, -mn));            \
                ls += pv_[ct][r];                                             \
            }                                                                 \
        ls += __shfl_xor(ls, 16);                                             \
        ls += __shfl_xor(ls, 32);                                             \
        lrun[rt] = lrun[rt] * alpha + ls;                                     \
        _Pragma("unroll")                                                     \
        for (int dct = 0; dct < 4; ++dct)                                     \
            _Pragma("unroll")                                                 \
            for (int r = 0; r < 4; ++r) oacc[rt][dct][r] *= alpha;            \
        const int prow_ = pbase + (rt * 16 + l15) * KVBLK;                    \
        _Pragma("unroll")                                                     \
        for (int ct = 0; ct < 4; ++ct) {                                      \
            u32 w01 = __builtin_bit_cast(u32,                                 \
                __builtin_amdgcn_cvt_pkrtz(pv_[ct][0], pv_[ct][1]));          \
            u32 w23 = __builtin_bit_cast(u32,                                 \
                __builtin_amdgcn_cvt_pkrtz(pv_[ct][2], pv_[ct][3]));          \
            *(u32x2*)&Pl[prow_ + ((4 * ct + lg) ^ l15) * 4] =                 \
                (u32x2){w01, w23};                                            \
        }                                                                     \
    }                                                                         \
    __builtin_amdgcn_s_setprio(1);                                            \
    _Pragma("unroll")                                                         \
    for (int ks2 = 0; ks2 < 2; ++ks2) {                                       \
        half8 pa[2];                                                          \
        _Pragma("unroll")                                                     \
        for (int rt = 0; rt < 2; ++rt) {                                      \
            const int prow_ = pbase + (rt * 16 + l15) * KVBLK;                \
            half4 plA_ = *(half4*)&Pl[prow_ + ((8 * ks2 + 2 * lg)     ^ l15) * 4]; \
            half4 plB_ = *(half4*)&Pl[prow_ + ((8 * ks2 + 2 * lg + 1) ^ l15) * 4]; \
            pa[rt] = __builtin_shufflevector(plA_, plB_, 0,1,2,3,4,5,6,7);    \
        }                                                                     \
        _Pragma("unroll")                                                     \
        for (int dct = 0; dct < 4; ++dct) {                                   \
            const int d = dct * 16 + l15;                                     \
            half8 vf = *(half8*)&VtC[d * KVBLK +                              \
                        (((ks2 * 4 + lg) ^ (d & 7) ^ (d >> 3)) * 8)];         \
            _Pragma("unroll")                                                 \
            for (int rt = 0; rt < 2; ++rt)                                    \
                oacc[rt][dct] = __builtin_amdgcn_mfma_f32_16x16x32_f16(       \
                    vf, pa[rt], oacc[rt][dct], 0, 0, 0);                      \
        }                                                                     \
    }                                                                         \
    __builtin_amdgcn_s_setprio(0);                                            \
    if (PF) { V_STORE(VtN, va_, vb_); }                                       \
    __syncthreads();                                                          \
} while (0)

__global__ __launch_bounds__(256, 2) void attn_mfma_kernel(
    const f16* __restrict__ qkvh, f16* __restrict__ attnh)
{
    __shared__ f16 Kh0[KVBLK * HD];       // 8 KB
    __shared__ f16 Kh1[KVBLK * HD];       // 8 KB
    __shared__ f16 Vt0[HD * KVBLK];       // 8 KB  [d][k]
    __shared__ f16 Vt1[HD * KVBLK];       // 8 KB
    __shared__ f16 Pl[4 * 32 * KVBLK];    // 16 KB per-wave [q][k]

    const int tid  = threadIdx.x;
    const int lane = tid & 63;
    const int wave = tid >> 6;
    const int l15  = lane & 15;
    const int lg   = lane >> 4;

    const int nq  = SEQ / QBLK;           // 16
    // XCD-chunked swizzle (kept from r5: FETCH 69.7 -> 21 MB)
    const int cpx = gridDim.x >> 3;
    const int lid = (blockIdx.x & 7) * cpx + (blockIdx.x >> 3);
    const int b   = lid / (NH * nq);
    const int h   = (lid / nq) % NH;
    const int qc  = lid % nq;
    const int q0  = qc * QBLK + wave * 32;
    const size_t bS = (size_t)b * SEQ;

    // K staging geometry: instr covers 8 rows x 8 chunks; row&7 == krow_l
    const int krow_l = lane >> 3;         // 0..7
    const int kschk  = (lane & 7) ^ krow_l;
    const f16* kxsrc = qkvh + bS * D3 + DM + h * HD + kschk * 8;

    // V staging geometry: thread = 2 k-rows x 8 d
    const int vp  = tid >> 3;             // 0..31
    const int vd0 = (tid & 7) * 8;
    const f16* vsrc0 = qkvh + (bS + 2 * vp) * D3 + 2 * DM + h * HD + vd0;

    // Q fragments (used as B-operand of swapped QK^T; same data layout)
    half8 qf[2][2];
#pragma unroll
    for (int rt = 0; rt < 2; ++rt)
#pragma unroll
        for (int ks = 0; ks < 2; ++ks)
            qf[rt][ks] = *(const half8*)&qkvh[(bS + q0 + rt * 16 + l15) * D3 +
                                              h * HD + ks * 32 + lg * 8];

    f32x4 oacc[2][4];   // O^T: oacc[rt][dct][r] = O[q=l15(+16rt)][d=dct*16+4lg+r]
#pragma unroll
    for (int rt = 0; rt < 2; ++rt)
#pragma unroll
        for (int dct = 0; dct < 4; ++dct) oacc[rt][dct] = (f32x4){0.f, 0.f, 0.f, 0.f};

    float mrun[2], lrun[2];
#pragma unroll
    for (int rt = 0; rt < 2; ++rt) { mrun[rt] = -INFINITY; lrun[rt] = 0.f; }

    const int pbase = wave * 32 * KVBLK;

    // prologue: stage tile 0 into buf0
    {
        async_cp16(kxsrc + (size_t)(wave * 16 +     krow_l) * D3, &Kh0[(wave * 16) * HD]);
        async_cp16(kxsrc + (size_t)(wave * 16 + 8 + krow_l) * D3, &Kh0[(wave * 16 + 8) * HD]);
        half8 va_ = *(const half8*)(vsrc0);
        half8 vb_ = *(const half8*)(vsrc0 + D3);
        V_STORE(Vt0, va_, vb_);
        __syncthreads();   // drains gload vmcnt + publishes Vt0
    }

    for (int t = 0; t < NTILES; t += 2) {
        ATTN_STEP(Kh0, Vt0, Kh1, Vt1, t, true);
        ATTN_STEP(Kh1, Vt1, Kh0, Vt0, t + 1, (t + 1) < (NTILES - 1));
    }

    // epilogue: O^T regs are contiguous-in-d -> half4 stores
#pragma unroll
    for (int rt = 0; rt < 2; ++rt) {
        const float inv = 1.f / lrun[rt];
        const int qq = q0 + rt * 16 + l15;
#pragma unroll
        for (int dct = 0; dct < 4; ++dct) {
            half4 o;
#pragma unroll
            for (int r = 0; r < 4; ++r) o[r] = (f16)(oacc[rt][dct][r] * inv);
            *(half4*)&attnh[(bS + qq) * DM + h * HD + dct * 16 + 4 * lg] = o;
        }
    }
}

// ---------------------------------------------------------------------------
extern "C" void kernel_launch(void* const* d_in, const int* in_sizes, int n_in,
                              void* d_out, int out_size, void* d_ws, size_t ws_size,
                              hipStream_t stream) {
    const float* q    = (const float*)d_in[0];
    const float* k    = (const float*)d_in[1];
    const float* v    = (const float*)d_in[2];
    const float* Wqkv = (const float*)d_in[3];
    const float* bqkv = (const float*)d_in[4];
    const float* Wo   = (const float*)d_in[5];
    const float* bo   = (const float*)d_in[6];
    float* out = (float*)d_out;

    char* ws = (char*)d_ws;
    f16* Ain    = (f16*)ws;                        // [4096][3072]
    f16* attn_h = (f16*)ws;                        // [4096][1024] (reuse)
    f16* Wo_h   = (f16*)(ws + 16777216);           // [1024][1024] (reuse)
    f16* Wqkv_h = (f16*)(ws + 25165824);           // [3072][3072]
    f16* qkv_h  = (f16*)(ws + 44040192);           // [4096][3072]

    conv_concat_kernel<<<dim3(3, MROWS), 256, 0, stream>>>(q, k, v, Ain);
    conv_plain_kernel<<<2048, 256, 0, stream>>>(Wqkv, Wqkv_h, D3 * D3 / 4);

    gemm_f16_kernel<D3, D3, true><<<dim3((MROWS / 128) * (D3 / 128)), 256, 0, stream>>>(
        Ain, Wqkv_h, bqkv, qkv_h);

    attn_mfma_kernel<<<dim3(BS * NH * (SEQ / QBLK)), 256, 0, stream>>>(qkv_h, attn_h);

    conv_plain_kernel<<<512, 256, 0, stream>>>(Wo, Wo_h, DM * DM / 4);

    gemm_f16_kernel<DM, DM, false><<<dim3((MROWS / 128) * (DM / 128)), 256, 0, stream>>>(
        attn_h, Wo_h, bo, out);
}